// Round 10
// baseline (1078.232 us; speedup 1.0000x reference)
//
#include <hip/hip_runtime.h>

#define NVAR 1000000
#define NCON 500000
#define EPB 8192     // edges per pass-A block

// ============================================================================
// Sort front-end: fused dual histogram, scans, LDS rank-stage scatter
// ============================================================================

// one pass over both edge arrays -> per-(bucket,block) counts for BOTH sorts
__global__ __launch_bounds__(256) void kA_hist2(const int4* __restrict__ src4,
                                                const int4* __restrict__ dst4,
                                                unsigned* __restrict__ bhV,
                                                unsigned* __restrict__ bhC,
                                                int ne4, int nblk) {
    __shared__ unsigned hv[1024], hc[1024];
    int tid = threadIdx.x, b = blockIdx.x;
    for (int t = tid; t < 1024; t += 256) { hv[t] = 0; hc[t] = 0; }
    __syncthreads();
    int beg = b * (EPB / 4), end = min(ne4, beg + (EPB / 4));
    for (int i = beg + tid; i < end; i += 256) {
        int4 s = src4[i];
        int4 d = dst4[i];
        atomicAdd(&hv[s.x >> 10], 1u); atomicAdd(&hv[s.y >> 10], 1u);
        atomicAdd(&hv[s.z >> 10], 1u); atomicAdd(&hv[s.w >> 10], 1u);
        atomicAdd(&hc[d.x >> 9], 1u);  atomicAdd(&hc[d.y >> 9], 1u);
        atomicAdd(&hc[d.z >> 9], 1u);  atomicAdd(&hc[d.w >> 9], 1u);
    }
    __syncthreads();
    for (int t = tid; t < 1024; t += 256) {
        bhV[(size_t)t * nblk + b] = hv[t];
        bhC[(size_t)t * nblk + b] = hc[t];
    }
}

// rank-stage payload in LDS, emit slots in order -> all global traffic sequential
__global__ __launch_bounds__(256) void kA_scat(const int* __restrict__ keys,
                                               const int* __restrict__ vals,
                                               const float* __restrict__ w,
                                               const unsigned int* __restrict__ scanned,
                                               int2* __restrict__ bucketed,
                                               int ne, int shift, int nblk) {
    __shared__ unsigned int h[1024];
    __shared__ unsigned int lb[1024];
    __shared__ unsigned int gb[1024];
    __shared__ unsigned int sc[256];
    __shared__ int2 stage[EPB];
    int tid = threadIdx.x, b = blockIdx.x;
    for (int t = tid; t < 1024; t += 256) {
        h[t] = 0;
        gb[t] = scanned[(size_t)t * nblk + b];
    }
    __syncthreads();
    int beg = b * EPB, end = min(ne, beg + EPB), cnt = end - beg;
    int cnt4 = cnt >> 2;
    const int4* keys4 = (const int4*)(keys + beg);
    for (int i = tid; i < cnt4; i += 256) {
        int4 k = keys4[i];
        atomicAdd(&h[k.x >> shift], 1u);
        atomicAdd(&h[k.y >> shift], 1u);
        atomicAdd(&h[k.z >> shift], 1u);
        atomicAdd(&h[k.w >> shift], 1u);
    }
    for (int i = cnt4 * 4 + tid; i < cnt; i += 256) atomicAdd(&h[keys[beg + i] >> shift], 1u);
    __syncthreads();
    unsigned v0, v1, v2, v3;
    int q = tid * 4;
    v0 = h[q]; v1 = h[q + 1]; v2 = h[q + 2]; v3 = h[q + 3];
    sc[tid] = v0 + v1 + v2 + v3;
    __syncthreads();
    for (int dd = 1; dd < 256; dd <<= 1) {
        unsigned add = (tid >= dd) ? sc[tid - dd] : 0u;
        __syncthreads();
        sc[tid] += add;
        __syncthreads();
    }
    unsigned ex = (tid == 0) ? 0u : sc[tid - 1];
    lb[q]     = ex;
    lb[q + 1] = ex + v0;
    lb[q + 2] = ex + v0 + v1;
    lb[q + 3] = ex + v0 + v1 + v2;
    __syncthreads();
    for (int t = tid; t < 1024; t += 256) h[t] = 0;
    __syncthreads();
    unsigned mask = (1u << shift) - 1u;
    const int4* vals4 = (const int4*)(vals + beg);
    const float4* w4 = (const float4*)(w + beg);
    for (int i = tid; i < cnt4; i += 256) {
        int4 k = keys4[i];
        int4 v = vals4[i];
        float4 ww = w4[i];
        {
            unsigned bkt = (unsigned)k.x >> shift;
            unsigned r = atomicAdd(&h[bkt], 1u);
            stage[lb[bkt] + r] = make_int2(__float_as_int(ww.x),
                                           (v.x << shift) | (unsigned)(k.x & (int)mask));
        }
        {
            unsigned bkt = (unsigned)k.y >> shift;
            unsigned r = atomicAdd(&h[bkt], 1u);
            stage[lb[bkt] + r] = make_int2(__float_as_int(ww.y),
                                           (v.y << shift) | (unsigned)(k.y & (int)mask));
        }
        {
            unsigned bkt = (unsigned)k.z >> shift;
            unsigned r = atomicAdd(&h[bkt], 1u);
            stage[lb[bkt] + r] = make_int2(__float_as_int(ww.z),
                                           (v.z << shift) | (unsigned)(k.z & (int)mask));
        }
        {
            unsigned bkt = (unsigned)k.w >> shift;
            unsigned r = atomicAdd(&h[bkt], 1u);
            stage[lb[bkt] + r] = make_int2(__float_as_int(ww.w),
                                           (v.w << shift) | (unsigned)(k.w & (int)mask));
        }
    }
    for (int i = cnt4 * 4 + tid; i < cnt; i += 256) {
        int k = keys[beg + i];
        unsigned bkt = (unsigned)k >> shift;
        unsigned r = atomicAdd(&h[bkt], 1u);
        stage[lb[bkt] + r] = make_int2(__float_as_int(w[beg + i]),
                                       (vals[beg + i] << shift) | (unsigned)(k & (int)mask));
    }
    __syncthreads();
    for (int i = tid; i < cnt; i += 256) {
        unsigned bb = 0;
#pragma unroll
        for (int step = 512; step > 0; step >>= 1) {
            unsigned cand = bb + step;
            if (cand < 1024 && lb[cand] <= (unsigned)i) bb = cand;
        }
        bucketed[gb[bb] + ((unsigned)i - lb[bb])] = stage[i];
    }
}

// light pass: per-bucket low-bit histogram of bucketedV -> deg_var
__global__ __launch_bounds__(256) void kB_degV(const int2* __restrict__ bucketed,
                                               const unsigned* __restrict__ scanned,
                                               unsigned* __restrict__ deg,
                                               int nnodes, int nblk) {
    __shared__ unsigned h[1024];
    int d = blockIdx.x, tid = threadIdx.x;
    unsigned base = scanned[(size_t)d * nblk], next = scanned[(size_t)(d + 1) * nblk];
    for (int t = tid; t < 1024; t += 256) h[t] = 0;
    __syncthreads();
    for (unsigned i = base + tid; i < next; i += 256)
        atomicAdd(&h[(unsigned)bucketed[i].y & 1023u], 1u);
    __syncthreads();
    int lo = d << 10;
    for (int t = tid; t < 1024; t += 256) {
        int node = lo + t;
        if (node < nnodes) deg[node] = h[t];
    }
}

__global__ __launch_bounds__(256) void k_scan_blocks(const unsigned int* __restrict__ in,
                                                     unsigned int* __restrict__ out,
                                                     unsigned int* __restrict__ bsum,
                                                     int n) {
    __shared__ unsigned int sT[256];
    int base = blockIdx.x * 1024 + threadIdx.x * 4;
    unsigned int v0 = 0, v1 = 0, v2 = 0, v3 = 0;
    if (base + 3 < n) {
        uint4 u = *(const uint4*)(in + base);
        v0 = u.x; v1 = u.y; v2 = u.z; v3 = u.w;
    } else {
        if (base     < n) v0 = in[base];
        if (base + 1 < n) v1 = in[base + 1];
        if (base + 2 < n) v2 = in[base + 2];
        if (base + 3 < n) v3 = in[base + 3];
    }
    sT[threadIdx.x] = v0 + v1 + v2 + v3;
    __syncthreads();
    for (int d = 1; d < 256; d <<= 1) {
        unsigned int add = (threadIdx.x >= (unsigned)d) ? sT[threadIdx.x - d] : 0u;
        __syncthreads();
        sT[threadIdx.x] += add;
        __syncthreads();
    }
    unsigned int excl = (threadIdx.x == 0) ? 0u : sT[threadIdx.x - 1];
    if (base     < n) out[base]     = excl;
    if (base + 1 < n) out[base + 1] = excl + v0;
    if (base + 2 < n) out[base + 2] = excl + v0 + v1;
    if (base + 3 < n) out[base + 3] = excl + v0 + v1 + v2;
    if (threadIdx.x == 255 && bsum) bsum[blockIdx.x] = sT[255];
}

__global__ __launch_bounds__(256) void k_scan_add(unsigned int* __restrict__ data,
                                                  const unsigned int* __restrict__ bscan,
                                                  int n) {
    int base = blockIdx.x * 1024 + threadIdx.x * 4;
    unsigned int add = bscan[blockIdx.x];
    if (base + 3 < n) {
        uint4 u = *(const uint4*)(data + base);
        u.x += add; u.y += add; u.z += add; u.w += add;
        *(uint4*)(data + base) = u;
    } else {
        if (base     < n) data[base]     += add;
        if (base + 1 < n) data[base + 1] += add;
        if (base + 2 < n) data[base + 2] += add;
        if (base + 3 < n) data[base + 3] += add;
    }
}

// ============================================================================
// Node pipeline
// ============================================================================

// var embedding -> [n][16] rows (10 used), prescaled by rsqrt(deg)
__global__ __launch_bounds__(256) void k_xvar_p(const float* __restrict__ var_c,
                                                const float* __restrict__ var_x,
                                                const unsigned int* __restrict__ deg_var,
                                                const float* __restrict__ Wv,
                                                const float* __restrict__ bv,
                                                float* __restrict__ Xs, int n) {
    int i = blockIdx.x * blockDim.x + threadIdx.x;
    if (i >= n) return;
    float c = var_c[i], x = var_x[i];
    float rs = rsqrtf(fmaxf((float)deg_var[i], 1.0f));
    float o[16];
#pragma unroll
    for (int j = 0; j < 10; j++) {
        float t = fmaf(c, Wv[j], fmaf(x, Wv[10 + j], bv[j]));
        o[j] = fmaxf(t, 0.0f) * rs;
    }
#pragma unroll
    for (int j = 10; j < 16; j++) o[j] = 0.0f;
    float4* dst4 = (float4*)(Xs + (size_t)i * 16);
#pragma unroll
    for (int j = 0; j < 4; j++)
        dst4[j] = make_float4(o[4 * j], o[4 * j + 1], o[4 * j + 2], o[4 * j + 3]);
}

#define EDGE_ADD(p, v)                                                        \
    {                                                                         \
        unsigned node_ = (unsigned)(p).y & mask;                              \
        float w_ = __int_as_float((p).x);                                     \
        if (lane == 0) atomicAdd(&hdeg[node_], 1u);                           \
        if (c0 < 10) {                                                        \
            float* a_ = &acc[node_ * 10 + c0];                                \
            atomicAdd(a_, w_ * (v).x);                                        \
            atomicAdd(a_ + 1, w_ * (v).y);                                    \
            if (c0 + 2 < 10) {                                                \
                atomicAdd(a_ + 2, w_ * (v).z);                                \
                atomicAdd(a_ + 3, w_ * (v).w);                                \
            }                                                                 \
        }                                                                     \
    }

// conv1 fused: per bucket of 512 con nodes, gather Xs rows per edge,
// LDS-accumulate, then dense layer + double prescale -> hs rows
__global__ __launch_bounds__(512) void kB_conv1(const int2* __restrict__ bucketed,
                                                const unsigned* __restrict__ scanned,
                                                const float* __restrict__ Xs,
                                                const float* __restrict__ W2,
                                                const float* __restrict__ b2,
                                                float* __restrict__ hs, int nblk) {
    __shared__ float acc[512 * 10];     // 20 KB
    __shared__ unsigned hdeg[512];
    __shared__ float sW[100], sb[10];
    const unsigned mask = 511u;
    int tid = threadIdx.x, d = blockIdx.x;
    for (int t = tid; t < 100; t += 512) sW[t] = W2[t];
    if (tid < 10) sb[tid] = b2[tid];
    for (int t = tid; t < 5120; t += 512) acc[t] = 0.f;
    if (tid < 512) hdeg[tid] = 0;
    __syncthreads();
    unsigned base = scanned[(size_t)d * nblk], next = scanned[(size_t)(d + 1) * nblk];
    int bsz = (int)(next - base);
    int quad = tid >> 2, lane = tid & 3, c0 = lane * 4;
    int i = quad;
    for (; i + 384 < bsz; i += 512) {
        int2 p0 = bucketed[base + i];
        int2 p1 = bucketed[base + i + 128];
        int2 p2 = bucketed[base + i + 256];
        int2 p3 = bucketed[base + i + 384];
        float4 v0 = *(const float4*)(Xs + ((size_t)((unsigned)p0.y >> 9)) * 16 + c0);
        float4 v1 = *(const float4*)(Xs + ((size_t)((unsigned)p1.y >> 9)) * 16 + c0);
        float4 v2 = *(const float4*)(Xs + ((size_t)((unsigned)p2.y >> 9)) * 16 + c0);
        float4 v3 = *(const float4*)(Xs + ((size_t)((unsigned)p3.y >> 9)) * 16 + c0);
        EDGE_ADD(p0, v0); EDGE_ADD(p1, v1); EDGE_ADD(p2, v2); EDGE_ADD(p3, v3);
    }
    for (; i < bsz; i += 128) {
        int2 p = bucketed[base + i];
        float4 v = *(const float4*)(Xs + ((size_t)((unsigned)p.y >> 9)) * 16 + c0);
        EDGE_ADD(p, v);
    }
    __syncthreads();
    int lo = d << 9;
    int node = tid;          // 512 nodes, 512 threads
    int g = lo + node;
    if (g < NCON) {
        float rs = rsqrtf(fmaxf((float)hdeg[node], 1.0f));
        float a[10];
#pragma unroll
        for (int j = 0; j < 10; j++) a[j] = acc[node * 10 + j] * rs;
        float o[16];
#pragma unroll
        for (int k = 0; k < 10; k++) {
            float t = sb[k];
#pragma unroll
            for (int j = 0; j < 10; j++) t = fmaf(a[j], sW[j * 10 + k], t);
            o[k] = fmaxf(t, 0.0f) * rs;   // relu + prescale for conv2
        }
#pragma unroll
        for (int k = 10; k < 16; k++) o[k] = 0.0f;
        float4* dst = (float4*)(hs + (size_t)g * 16);
        dst[0] = make_float4(o[0], o[1], o[2], o[3]);
        dst[1] = make_float4(o[4], o[5], o[6], o[7]);
        dst[2] = make_float4(o[8], o[9], o[10], o[11]);
        dst[3] = make_float4(o[12], o[13], o[14], o[15]);
    }
}

// conv2 fused: per bucket of 1024 var nodes, gather hs rows per edge,
// LDS-accumulate, then dense + 3-layer MLP + bucket partial mean
__global__ __launch_bounds__(512) void kB_conv2(const int2* __restrict__ bucketed,
                                                const unsigned* __restrict__ scanned,
                                                const float* __restrict__ hs,
                                                const float* __restrict__ W2,
                                                const float* __restrict__ b2,
                                                const float* __restrict__ Wo1,
                                                const float* __restrict__ bo1,
                                                const float* __restrict__ Wo2,
                                                const float* __restrict__ bo2,
                                                const float* __restrict__ Wo3,
                                                const float* __restrict__ bo3,
                                                double* __restrict__ partials, int nblk) {
    __shared__ float acc[1024 * 10];    // 40 KB
    __shared__ unsigned hdeg[1024];
    __shared__ float sW2[100], sb2[10], sWo1[100], sbo1[10], sWo2[100], sbo2[10], sWo3[10], sbo3v;
    __shared__ double red[512];
    const unsigned mask = 1023u;
    int tid = threadIdx.x, d = blockIdx.x;
    for (int t = tid; t < 100; t += 512) { sW2[t] = W2[t]; sWo1[t] = Wo1[t]; sWo2[t] = Wo2[t]; }
    if (tid < 10) {
        sb2[tid] = b2[tid]; sbo1[tid] = bo1[tid]; sbo2[tid] = bo2[tid]; sWo3[tid] = Wo3[tid];
    }
    if (tid == 0) sbo3v = bo3[0];
    for (int t = tid; t < 10240; t += 512) acc[t] = 0.f;
    for (int t = tid; t < 1024; t += 512) hdeg[t] = 0;
    __syncthreads();
    unsigned base = scanned[(size_t)d * nblk], next = scanned[(size_t)(d + 1) * nblk];
    int bsz = (int)(next - base);
    int quad = tid >> 2, lane = tid & 3, c0 = lane * 4;
    int i = quad;
    for (; i + 384 < bsz; i += 512) {
        int2 p0 = bucketed[base + i];
        int2 p1 = bucketed[base + i + 128];
        int2 p2 = bucketed[base + i + 256];
        int2 p3 = bucketed[base + i + 384];
        float4 v0 = *(const float4*)(hs + ((size_t)((unsigned)p0.y >> 10)) * 16 + c0);
        float4 v1 = *(const float4*)(hs + ((size_t)((unsigned)p1.y >> 10)) * 16 + c0);
        float4 v2 = *(const float4*)(hs + ((size_t)((unsigned)p2.y >> 10)) * 16 + c0);
        float4 v3 = *(const float4*)(hs + ((size_t)((unsigned)p3.y >> 10)) * 16 + c0);
        EDGE_ADD(p0, v0); EDGE_ADD(p1, v1); EDGE_ADD(p2, v2); EDGE_ADD(p3, v3);
    }
    for (; i < bsz; i += 128) {
        int2 p = bucketed[base + i];
        float4 v = *(const float4*)(hs + ((size_t)((unsigned)p.y >> 10)) * 16 + c0);
        EDGE_ADD(p, v);
    }
    __syncthreads();
    double accd = 0.0;
    int lo = d << 10;
#pragma unroll
    for (int r = 0; r < 2; r++) {
        int node = r * 512 + tid;
        int g = lo + node;
        if (g < NVAR) {
            float rs = rsqrtf(fmaxf((float)hdeg[node], 1.0f));
            float a[10], h[10], z[10];
#pragma unroll
            for (int j = 0; j < 10; j++) a[j] = acc[node * 10 + j] * rs;
#pragma unroll
            for (int k = 0; k < 10; k++) {
                float t = sb2[k];
#pragma unroll
                for (int j = 0; j < 10; j++) t = fmaf(a[j], sW2[j * 10 + k], t);
                h[k] = fmaxf(t, 0.0f);
            }
#pragma unroll
            for (int k = 0; k < 10; k++) {
                float t = sbo1[k];
#pragma unroll
                for (int j = 0; j < 10; j++) t = fmaf(h[j], sWo1[j * 10 + k], t);
                z[k] = fmaxf(t, 0.0f);
            }
            float t3 = sbo3v;
#pragma unroll
            for (int k = 0; k < 10; k++) {
                float t = sbo2[k];
#pragma unroll
                for (int j = 0; j < 10; j++) t = fmaf(z[j], sWo2[j * 10 + k], t);
                t = fmaxf(t, 0.0f);
                t3 = fmaf(t, sWo3[k], t3);
            }
            accd += (double)t3;
        }
    }
    red[tid] = accd;
    __syncthreads();
    for (int off = 256; off > 0; off >>= 1) {
        if (tid < off) red[tid] += red[tid + off];
        __syncthreads();
    }
    if (tid == 0) partials[d] = red[0];
}

__global__ __launch_bounds__(256) void k_out(const double* __restrict__ partials, int np,
                                             float* __restrict__ out) {
    __shared__ double red[256];
    double a = 0.0;
    for (int i = threadIdx.x; i < np; i += blockDim.x) a += partials[i];
    red[threadIdx.x] = a;
    __syncthreads();
    for (int off = 128; off > 0; off >>= 1) {
        if (threadIdx.x < off) red[threadIdx.x] += red[threadIdx.x + off];
        __syncthreads();
    }
    if (threadIdx.x == 0) out[0] = (float)(red[0] / (double)NVAR);
}

// ============================================================================
// Launch
// ============================================================================

extern "C" void kernel_launch(void* const* d_in, const int* in_sizes, int n_in,
                              void* d_out, int out_size, void* d_ws, size_t ws_size,
                              hipStream_t stream) {
    const float* var_c  = (const float*)d_in[0];
    const float* var_x  = (const float*)d_in[1];
    const int*   e_src  = (const int*)d_in[3];
    const int*   e_dst  = (const int*)d_in[4];
    const float* e_w    = (const float*)d_in[5];
    const float* Wv     = (const float*)d_in[6];
    const float* bv     = (const float*)d_in[7];
    const float* W2     = (const float*)d_in[12];
    const float* b2     = (const float*)d_in[13];
    const float* Wo1    = (const float*)d_in[14];
    const float* bo1    = (const float*)d_in[15];
    const float* Wo2    = (const float*)d_in[16];
    const float* bo2    = (const float*)d_in[17];
    const float* Wo3    = (const float*)d_in[18];
    const float* bo3    = (const float*)d_in[19];
    float* out = (float*)d_out;
    const int ne = in_sizes[3];
    (void)n_in; (void)out_size; (void)ws_size;

    const int B = 256;
    const int nblkA = (ne + EPB - 1) / EPB;       // 977
    const int scanN = 1024 * nblkA;
    const int NBs   = (scanN + 1023) / 1024;
    const int BKV   = (NVAR + 1023) >> 10;        // 977 (shift 10)
    const int BKC   = (NCON + 511) >> 9;          // 977 (shift 9)
    const int ne4   = ne / 4;

    char* ws = (char*)d_ws;
    size_t off = 0;
    auto walloc = [&](size_t bytes) {
        void* p = ws + off;
        off = (off + bytes + 255) & ~(size_t)255;
        return p;
    };

    int2*     bucketedV = (int2*)walloc((size_t)ne * 8);           // 64 MB
    int2*     bucketedC = (int2*)walloc((size_t)ne * 8);           // 64 MB
    float*    Xs64      = (float*)walloc((size_t)NVAR * 16 * 4);   // 64 MB
    float*    hs64      = (float*)walloc((size_t)NCON * 16 * 4);   // 32 MB
    unsigned* scannedV  = (unsigned*)walloc((size_t)scanN * 4);    //  4 MB
    unsigned* scannedC  = (unsigned*)walloc((size_t)scanN * 4);    //  4 MB
    unsigned* bhV       = (unsigned*)walloc((size_t)scanN * 4);    //  4 MB
    unsigned* bhC       = (unsigned*)walloc((size_t)scanN * 4);    //  4 MB
    unsigned* bsumV     = (unsigned*)walloc(4096);
    unsigned* bscanV    = (unsigned*)walloc(4096);
    unsigned* bsumC     = (unsigned*)walloc(4096);
    unsigned* bscanC    = (unsigned*)walloc(4096);
    unsigned* bdummy    = (unsigned*)walloc(256);
    // overlays: bhV dead after scanV -> deg_var; bhC dead after scanC -> partials
    unsigned* deg_var   = bhV;                                     // 4 MB needed
    double*   partials  = (double*)bhC;                            // 977 doubles

    // 1. fused dual histogram (one pass over both edge arrays)
    kA_hist2<<<nblkA, B, 0, stream>>>((const int4*)e_src, (const int4*)e_dst,
                                      bhV, bhC, ne4, nblkA);

    // 2. scans -> global segment bases for both sorts
    k_scan_blocks<<<NBs, B, 0, stream>>>(bhV, scannedV, bsumV, scanN);
    k_scan_blocks<<<1,   B, 0, stream>>>(bsumV, bscanV, bdummy, NBs);
    k_scan_add   <<<NBs, B, 0, stream>>>(scannedV, bscanV, scanN);
    k_scan_blocks<<<NBs, B, 0, stream>>>(bhC, scannedC, bsumC, scanN);
    k_scan_blocks<<<1,   B, 0, stream>>>(bsumC, bscanC, bdummy, NBs);
    k_scan_add   <<<NBs, B, 0, stream>>>(scannedC, bscanC, scanN);

    // 3. V-direction bucketing (key=src var, val=dst con)
    kA_scat<<<nblkA, B, 0, stream>>>(e_src, e_dst, e_w, scannedV, bucketedV, ne, 10, nblkA);

    // 4. deg_var (needed for Xs prescale); overlays bhV (dead after scanV)
    kB_degV<<<BKV, B, 0, stream>>>(bucketedV, scannedV, deg_var, NVAR, nblkA);

    // 5. var embedding (prescaled, 64 B rows)
    k_xvar_p<<<(NVAR + B - 1) / B, B, 0, stream>>>(var_c, var_x, deg_var, Wv, bv, Xs64, NVAR);

    // 6. C-direction bucketing (key=dst con, val=src var)
    kA_scat<<<nblkA, B, 0, stream>>>(e_dst, e_src, e_w, scannedC, bucketedC, ne, 9, nblkA);

    // 7. conv1 fused: bucketedC + Xs gathers -> hs rows (no CSR materialized)
    kB_conv1<<<BKC, 512, 0, stream>>>(bucketedC, scannedC, Xs64, W2, b2, hs64, nblkA);

    // 8. conv2 fused: bucketedV + hs gathers -> MLP -> per-bucket partial sums
    kB_conv2<<<BKV, 512, 0, stream>>>(bucketedV, scannedV, hs64, W2, b2,
                                      Wo1, bo1, Wo2, bo2, Wo3, bo3, partials, nblkA);

    // 9. final mean
    k_out<<<1, B, 0, stream>>>(partials, BKV, out);
}

// Round 11
// 579.988 us; speedup vs baseline: 1.8591x; 1.8591x over previous
//
#include <hip/hip_runtime.h>

#define NVAR 1000000
#define NCON 500000
#define EPB 8192     // edges per pass-A block
#define FCAP 4480    // per-half-bucket LDS stage capacity (mean 4096, sd 64 -> +6 sigma)

// ============================================================================
// Sort front-end
// ============================================================================

// one pass over both edge arrays -> per-(bucket,block) counts for BOTH sorts
__global__ __launch_bounds__(256) void kA_hist2(const int4* __restrict__ src4,
                                                const int4* __restrict__ dst4,
                                                unsigned* __restrict__ bhV,
                                                unsigned* __restrict__ bhC,
                                                int ne4, int nblk) {
    __shared__ unsigned hv[1024], hc[1024];
    int tid = threadIdx.x, b = blockIdx.x;
    for (int t = tid; t < 1024; t += 256) { hv[t] = 0; hc[t] = 0; }
    __syncthreads();
    int beg = b * (EPB / 4), end = min(ne4, beg + (EPB / 4));
    for (int i = beg + tid; i < end; i += 256) {
        int4 s = src4[i];
        int4 d = dst4[i];
        atomicAdd(&hv[s.x >> 10], 1u); atomicAdd(&hv[s.y >> 10], 1u);
        atomicAdd(&hv[s.z >> 10], 1u); atomicAdd(&hv[s.w >> 10], 1u);
        atomicAdd(&hc[d.x >> 9], 1u);  atomicAdd(&hc[d.y >> 9], 1u);
        atomicAdd(&hc[d.z >> 9], 1u);  atomicAdd(&hc[d.w >> 9], 1u);
    }
    __syncthreads();
    for (int t = tid; t < 1024; t += 256) {
        bhV[(size_t)t * nblk + b] = hv[t];
        bhC[(size_t)t * nblk + b] = hc[t];
    }
}

// rank-stage payload in LDS, emit slots in order -> all global traffic sequential
__global__ __launch_bounds__(256) void kA_scat(const int* __restrict__ keys,
                                               const int* __restrict__ vals,
                                               const float* __restrict__ w,
                                               const unsigned int* __restrict__ scanned,
                                               int2* __restrict__ bucketed,
                                               int ne, int shift, int nblk) {
    __shared__ unsigned int h[1024];
    __shared__ unsigned int lb[1024];
    __shared__ unsigned int gb[1024];
    __shared__ unsigned int sc[256];
    __shared__ int2 stage[EPB];
    int tid = threadIdx.x, b = blockIdx.x;
    for (int t = tid; t < 1024; t += 256) {
        h[t] = 0;
        gb[t] = scanned[(size_t)t * nblk + b];
    }
    __syncthreads();
    int beg = b * EPB, end = min(ne, beg + EPB), cnt = end - beg;
    int cnt4 = cnt >> 2;
    const int4* keys4 = (const int4*)(keys + beg);
    for (int i = tid; i < cnt4; i += 256) {
        int4 k = keys4[i];
        atomicAdd(&h[k.x >> shift], 1u);
        atomicAdd(&h[k.y >> shift], 1u);
        atomicAdd(&h[k.z >> shift], 1u);
        atomicAdd(&h[k.w >> shift], 1u);
    }
    for (int i = cnt4 * 4 + tid; i < cnt; i += 256) atomicAdd(&h[keys[beg + i] >> shift], 1u);
    __syncthreads();
    unsigned v0, v1, v2, v3;
    int q = tid * 4;
    v0 = h[q]; v1 = h[q + 1]; v2 = h[q + 2]; v3 = h[q + 3];
    sc[tid] = v0 + v1 + v2 + v3;
    __syncthreads();
    for (int dd = 1; dd < 256; dd <<= 1) {
        unsigned add = (tid >= dd) ? sc[tid - dd] : 0u;
        __syncthreads();
        sc[tid] += add;
        __syncthreads();
    }
    unsigned ex = (tid == 0) ? 0u : sc[tid - 1];
    lb[q]     = ex;
    lb[q + 1] = ex + v0;
    lb[q + 2] = ex + v0 + v1;
    lb[q + 3] = ex + v0 + v1 + v2;
    __syncthreads();
    for (int t = tid; t < 1024; t += 256) h[t] = 0;
    __syncthreads();
    unsigned mask = (1u << shift) - 1u;
    const int4* vals4 = (const int4*)(vals + beg);
    const float4* w4 = (const float4*)(w + beg);
    for (int i = tid; i < cnt4; i += 256) {
        int4 k = keys4[i];
        int4 v = vals4[i];
        float4 ww = w4[i];
        {
            unsigned bkt = (unsigned)k.x >> shift;
            unsigned r = atomicAdd(&h[bkt], 1u);
            stage[lb[bkt] + r] = make_int2(__float_as_int(ww.x),
                                           (v.x << shift) | (unsigned)(k.x & (int)mask));
        }
        {
            unsigned bkt = (unsigned)k.y >> shift;
            unsigned r = atomicAdd(&h[bkt], 1u);
            stage[lb[bkt] + r] = make_int2(__float_as_int(ww.y),
                                           (v.y << shift) | (unsigned)(k.y & (int)mask));
        }
        {
            unsigned bkt = (unsigned)k.z >> shift;
            unsigned r = atomicAdd(&h[bkt], 1u);
            stage[lb[bkt] + r] = make_int2(__float_as_int(ww.z),
                                           (v.z << shift) | (unsigned)(k.z & (int)mask));
        }
        {
            unsigned bkt = (unsigned)k.w >> shift;
            unsigned r = atomicAdd(&h[bkt], 1u);
            stage[lb[bkt] + r] = make_int2(__float_as_int(ww.w),
                                           (v.w << shift) | (unsigned)(k.w & (int)mask));
        }
    }
    for (int i = cnt4 * 4 + tid; i < cnt; i += 256) {
        int k = keys[beg + i];
        unsigned bkt = (unsigned)k >> shift;
        unsigned r = atomicAdd(&h[bkt], 1u);
        stage[lb[bkt] + r] = make_int2(__float_as_int(w[beg + i]),
                                       (vals[beg + i] << shift) | (unsigned)(k & (int)mask));
    }
    __syncthreads();
    for (int i = tid; i < cnt; i += 256) {
        unsigned bb = 0;
#pragma unroll
        for (int step = 512; step > 0; step >>= 1) {
            unsigned cand = bb + step;
            if (cand < 1024 && lb[cand] <= (unsigned)i) bb = cand;
        }
        bucketed[gb[bb] + ((unsigned)i - lb[bb])] = stage[i];
    }
}

// per-bucket low-bit histogram of bucketedV -> deg_var (needed before k_xvar_p)
__global__ __launch_bounds__(256) void kB_degV(const int2* __restrict__ bucketed,
                                               const unsigned* __restrict__ scanned,
                                               unsigned* __restrict__ deg,
                                               int nnodes, int nblk) {
    __shared__ unsigned h[1024];
    int d = blockIdx.x, tid = threadIdx.x;
    unsigned base = scanned[(size_t)d * nblk], next = scanned[(size_t)(d + 1) * nblk];
    for (int t = tid; t < 1024; t += 256) h[t] = 0;
    __syncthreads();
    for (unsigned i = base + tid; i < next; i += 256)
        atomicAdd(&h[(unsigned)bucketed[i].y & 1023u], 1u);
    __syncthreads();
    int lo = d << 10;
    for (int t = tid; t < 1024; t += 256) {
        int node = lo + t;
        if (node < nnodes) deg[node] = h[t];
    }
}

__global__ __launch_bounds__(256) void k_scan_blocks(const unsigned int* __restrict__ in,
                                                     unsigned int* __restrict__ out,
                                                     unsigned int* __restrict__ bsum,
                                                     int n) {
    __shared__ unsigned int sT[256];
    int base = blockIdx.x * 1024 + threadIdx.x * 4;
    unsigned int v0 = 0, v1 = 0, v2 = 0, v3 = 0;
    if (base + 3 < n) {
        uint4 u = *(const uint4*)(in + base);
        v0 = u.x; v1 = u.y; v2 = u.z; v3 = u.w;
    } else {
        if (base     < n) v0 = in[base];
        if (base + 1 < n) v1 = in[base + 1];
        if (base + 2 < n) v2 = in[base + 2];
        if (base + 3 < n) v3 = in[base + 3];
    }
    sT[threadIdx.x] = v0 + v1 + v2 + v3;
    __syncthreads();
    for (int d = 1; d < 256; d <<= 1) {
        unsigned int add = (threadIdx.x >= (unsigned)d) ? sT[threadIdx.x - d] : 0u;
        __syncthreads();
        sT[threadIdx.x] += add;
        __syncthreads();
    }
    unsigned int excl = (threadIdx.x == 0) ? 0u : sT[threadIdx.x - 1];
    if (base     < n) out[base]     = excl;
    if (base + 1 < n) out[base + 1] = excl + v0;
    if (base + 2 < n) out[base + 2] = excl + v0 + v1;
    if (base + 3 < n) out[base + 3] = excl + v0 + v1 + v2;
    if (threadIdx.x == 255 && bsum) bsum[blockIdx.x] = sT[255];
}

__global__ __launch_bounds__(256) void k_scan_add(unsigned int* __restrict__ data,
                                                  const unsigned int* __restrict__ bscan,
                                                  int n) {
    int base = blockIdx.x * 1024 + threadIdx.x * 4;
    unsigned int add = bscan[blockIdx.x];
    if (base + 3 < n) {
        uint4 u = *(const uint4*)(data + base);
        u.x += add; u.y += add; u.z += add; u.w += add;
        *(uint4*)(data + base) = u;
    } else {
        if (base     < n) data[base]     += add;
        if (base + 1 < n) data[base + 1] += add;
        if (base + 2 < n) data[base + 2] += add;
        if (base + 3 < n) data[base + 3] += add;
    }
}

// ============================================================================
// Node pipeline
// ============================================================================

__global__ __launch_bounds__(256) void k_xvar_p(const float* __restrict__ var_c,
                                                const float* __restrict__ var_x,
                                                const unsigned int* __restrict__ deg_var,
                                                const float* __restrict__ Wv,
                                                const float* __restrict__ bv,
                                                float* __restrict__ Xs, int n) {
    int i = blockIdx.x * blockDim.x + threadIdx.x;
    if (i >= n) return;
    float c = var_c[i], x = var_x[i];
    float rs = rsqrtf(fmaxf((float)deg_var[i], 1.0f));
    float o[16];
#pragma unroll
    for (int j = 0; j < 10; j++) {
        float t = fmaf(c, Wv[j], fmaf(x, Wv[10 + j], bv[j]));
        o[j] = fmaxf(t, 0.0f) * rs;
    }
#pragma unroll
    for (int j = 10; j < 16; j++) o[j] = 0.0f;
    float4* dst4 = (float4*)(Xs + (size_t)i * 16);
#pragma unroll
    for (int j = 0; j < 4; j++)
        dst4[j] = make_float4(o[4 * j], o[4 * j + 1], o[4 * j + 2], o[4 * j + 3]);
}

#define GATHER4(eA, eB, eC, eD, TAB)                                          \
    {                                                                         \
        float4 v0 = *(const float4*)(TAB + (size_t)(eA).y * 16 + c0);         \
        float4 v1 = *(const float4*)(TAB + (size_t)(eB).y * 16 + c0);         \
        float4 v2 = *(const float4*)(TAB + (size_t)(eC).y * 16 + c0);         \
        float4 v3 = *(const float4*)(TAB + (size_t)(eD).y * 16 + c0);         \
        float w0 = __int_as_float((eA).x), w1 = __int_as_float((eB).x);       \
        float w2 = __int_as_float((eC).x), w3 = __int_as_float((eD).x);       \
        acc.x = fmaf(w0, v0.x, acc.x); acc.y = fmaf(w0, v0.y, acc.y);         \
        acc.z = fmaf(w0, v0.z, acc.z); acc.w = fmaf(w0, v0.w, acc.w);         \
        acc.x = fmaf(w1, v1.x, acc.x); acc.y = fmaf(w1, v1.y, acc.y);         \
        acc.z = fmaf(w1, v1.z, acc.z); acc.w = fmaf(w1, v1.w, acc.w);         \
        acc.x = fmaf(w2, v2.x, acc.x); acc.y = fmaf(w2, v2.y, acc.y);         \
        acc.z = fmaf(w2, v2.z, acc.z); acc.w = fmaf(w2, v2.w, acc.w);         \
        acc.x = fmaf(w3, v3.x, acc.x); acc.y = fmaf(w3, v3.y, acc.y);         \
        acc.z = fmaf(w3, v3.z, acc.z); acc.w = fmaf(w3, v3.w, acc.w);         \
    }

// conv1 fused: half-bucket of 256 con nodes. Rank-stage sorted edges in LDS,
// quad-gather Xs rows (register accumulate), dense layer, write hs rows.
__global__ __launch_bounds__(512) void kF_con(const int2* __restrict__ bucketed,
                                              const unsigned* __restrict__ scanned,
                                              const float* __restrict__ Xs,
                                              const float* __restrict__ W2,
                                              const float* __restrict__ b2,
                                              float* __restrict__ hs, int nblk) {
    __shared__ unsigned h[512], s[512], tmp[512];
    __shared__ float sW[100], sb[10];
    __shared__ int2 stage[FCAP];
    int tid = threadIdx.x;
    int d = blockIdx.x >> 1, half = blockIdx.x & 1;
    for (int t = tid; t < 100; t += 512) sW[t] = W2[t];
    if (tid < 10) sb[tid] = b2[tid];
    h[tid] = 0;
    __syncthreads();
    unsigned base = scanned[(size_t)d * nblk];
    unsigned next = scanned[(size_t)(d + 1) * nblk];
    int bsz = (int)(next - base);
    for (int i = tid; i < bsz; i += 512)
        atomicAdd(&h[(unsigned)bucketed[base + i].y & 511u], 1u);
    __syncthreads();
    unsigned hv = h[tid];
    tmp[tid] = hv;
    __syncthreads();
    for (int dd = 1; dd < 512; dd <<= 1) {
        unsigned add = (tid >= dd) ? tmp[tid - dd] : 0u;
        __syncthreads();
        tmp[tid] += add;
        __syncthreads();
    }
    s[tid] = tmp[tid] - hv;
    __syncthreads();
    int hb = half * 256;
    unsigned own_beg = s[hb];
    unsigned own_end = (hb + 256 == 512) ? (unsigned)bsz : s[hb + 256];
    bool fit = (int)(own_end - own_beg) <= FCAP;
    h[tid] = 0;
    __syncthreads();
    if (fit) {
        for (int i = tid; i < bsz; i += 512) {
            int2 p = bucketed[base + i];
            unsigned low = (unsigned)p.y & 511u;
            if ((int)(low >> 8) == half) {
                unsigned r = atomicAdd(&h[low], 1u);
                stage[s[low] + r - own_beg] = make_int2(p.x, p.y >> 9);
            }
        }
    }
    __syncthreads();
    int quad = tid >> 2, lane = tid & 3, c0 = lane * 4;
#pragma unroll
    for (int rr = 0; rr < 2; rr++) {
        int node = hb + rr * 128 + quad;
        int g = (d << 9) + node;
        if (g >= NCON) continue;
        float4 acc = make_float4(0.f, 0.f, 0.f, 0.f);
        unsigned cnt;
        if (fit) {
            unsigned beg = s[node] - own_beg;
            cnt = h[node];
            unsigned end = beg + cnt, p = beg;
            for (; p + 4 <= end; p += 4) {
                int2 e0 = stage[p], e1 = stage[p + 1], e2 = stage[p + 2], e3 = stage[p + 3];
                GATHER4(e0, e1, e2, e3, Xs);
            }
            for (; p < end; ++p) {
                int2 e = stage[p];
                float4 v = *(const float4*)(Xs + (size_t)e.y * 16 + c0);
                float we = __int_as_float(e.x);
                acc.x = fmaf(we, v.x, acc.x); acc.y = fmaf(we, v.y, acc.y);
                acc.z = fmaf(we, v.z, acc.z); acc.w = fmaf(we, v.w, acc.w);
            }
        } else {   // statistically unreachable safety path
            cnt = 0;
            for (int i = 0; i < bsz; ++i) {
                int2 p = bucketed[base + i];
                if (((unsigned)p.y & 511u) == (unsigned)node) {
                    ++cnt;
                    float4 v = *(const float4*)(Xs + (size_t)((unsigned)p.y >> 9) * 16 + c0);
                    float we = __int_as_float(p.x);
                    acc.x = fmaf(we, v.x, acc.x); acc.y = fmaf(we, v.y, acc.y);
                    acc.z = fmaf(we, v.z, acc.z); acc.w = fmaf(we, v.w, acc.w);
                }
            }
        }
        float rs = rsqrtf(fmaxf((float)cnt, 1.0f));
        float a[10];
        a[0] = __shfl(acc.x, 0, 4); a[1] = __shfl(acc.y, 0, 4);
        a[2] = __shfl(acc.z, 0, 4); a[3] = __shfl(acc.w, 0, 4);
        a[4] = __shfl(acc.x, 1, 4); a[5] = __shfl(acc.y, 1, 4);
        a[6] = __shfl(acc.z, 1, 4); a[7] = __shfl(acc.w, 1, 4);
        a[8] = __shfl(acc.x, 2, 4); a[9] = __shfl(acc.y, 2, 4);
#pragma unroll
        for (int j = 0; j < 10; j++) a[j] *= rs;
        float o[12];
#pragma unroll
        for (int k = 0; k < 10; k++) {
            float t = sb[k];
#pragma unroll
            for (int j = 0; j < 10; j++) t = fmaf(a[j], sW[j * 10 + k], t);
            o[k] = fmaxf(t, 0.0f) * rs;   // relu + prescale for conv2
        }
        o[10] = 0.0f; o[11] = 0.0f;
        float4 wv = (lane < 3) ? make_float4(o[c0], o[c0 + 1], o[c0 + 2], o[c0 + 3])
                               : make_float4(0.f, 0.f, 0.f, 0.f);
        *(float4*)(hs + (size_t)g * 16 + c0) = wv;
    }
}

// conv2 fused: half-bucket of 512 var nodes. Rank-stage, quad-gather hs rows,
// dense + 3-layer MLP, per-block partial mean.
__global__ __launch_bounds__(512) void kF_fin(const int2* __restrict__ bucketed,
                                              const unsigned* __restrict__ scanned,
                                              const float* __restrict__ feat,
                                              const float* __restrict__ W2,
                                              const float* __restrict__ b2,
                                              const float* __restrict__ Wo1,
                                              const float* __restrict__ bo1,
                                              const float* __restrict__ Wo2,
                                              const float* __restrict__ bo2,
                                              const float* __restrict__ Wo3,
                                              const float* __restrict__ bo3,
                                              double* __restrict__ partials, int nblk) {
    __shared__ unsigned h[1024], s[1024], tmp[512];
    __shared__ float sW2[100], sb2[10], sWo1[100], sbo1[10], sWo2[100], sbo2[10], sWo3[10], sbo3v;
    __shared__ int2 stage[FCAP];
    __shared__ double red[512];
    int tid = threadIdx.x;
    int d = blockIdx.x >> 1, half = blockIdx.x & 1;
    for (int t = tid; t < 100; t += 512) { sW2[t] = W2[t]; sWo1[t] = Wo1[t]; sWo2[t] = Wo2[t]; }
    if (tid < 10) {
        sb2[tid] = b2[tid]; sbo1[tid] = bo1[tid]; sbo2[tid] = bo2[tid]; sWo3[tid] = Wo3[tid];
    }
    if (tid == 0) sbo3v = bo3[0];
    h[tid] = 0; h[tid + 512] = 0;
    __syncthreads();
    unsigned base = scanned[(size_t)d * nblk];
    unsigned next = scanned[(size_t)(d + 1) * nblk];
    int bsz = (int)(next - base);
    for (int i = tid; i < bsz; i += 512)
        atomicAdd(&h[(unsigned)bucketed[base + i].y & 1023u], 1u);
    __syncthreads();
    int q = tid * 2;
    unsigned v0 = h[q], v1 = h[q + 1];
    tmp[tid] = v0 + v1;
    __syncthreads();
    for (int dd = 1; dd < 512; dd <<= 1) {
        unsigned add = (tid >= dd) ? tmp[tid - dd] : 0u;
        __syncthreads();
        tmp[tid] += add;
        __syncthreads();
    }
    unsigned excl = tmp[tid] - (v0 + v1);
    s[q] = excl; s[q + 1] = excl + v0;
    __syncthreads();
    int hb = half * 512;
    unsigned own_beg = s[hb];
    unsigned own_end = (hb + 512 == 1024) ? (unsigned)bsz : s[hb + 512];
    bool fit = (int)(own_end - own_beg) <= FCAP;
    h[tid] = 0; h[tid + 512] = 0;
    __syncthreads();
    if (fit) {
        for (int i = tid; i < bsz; i += 512) {
            int2 p = bucketed[base + i];
            unsigned low = (unsigned)p.y & 1023u;
            if ((int)(low >> 9) == half) {
                unsigned r = atomicAdd(&h[low], 1u);
                stage[s[low] + r - own_beg] = make_int2(p.x, p.y >> 10);
            }
        }
    }
    __syncthreads();
    int quad = tid >> 2, lane = tid & 3, c0 = lane * 4;
    double accd = 0.0;
#pragma unroll
    for (int rr = 0; rr < 4; rr++) {
        int node = hb + rr * 128 + quad;
        int g = (d << 10) + node;
        if (g >= NVAR) continue;
        float4 acc = make_float4(0.f, 0.f, 0.f, 0.f);
        unsigned cnt;
        if (fit) {
            unsigned beg = s[node] - own_beg;
            cnt = h[node];
            unsigned end = beg + cnt, p = beg;
            for (; p + 4 <= end; p += 4) {
                int2 e0 = stage[p], e1 = stage[p + 1], e2 = stage[p + 2], e3 = stage[p + 3];
                GATHER4(e0, e1, e2, e3, feat);
            }
            for (; p < end; ++p) {
                int2 e = stage[p];
                float4 v = *(const float4*)(feat + (size_t)e.y * 16 + c0);
                float we = __int_as_float(e.x);
                acc.x = fmaf(we, v.x, acc.x); acc.y = fmaf(we, v.y, acc.y);
                acc.z = fmaf(we, v.z, acc.z); acc.w = fmaf(we, v.w, acc.w);
            }
        } else {   // statistically unreachable safety path
            cnt = 0;
            for (int i = 0; i < bsz; ++i) {
                int2 p = bucketed[base + i];
                if (((unsigned)p.y & 1023u) == (unsigned)node) {
                    ++cnt;
                    float4 v = *(const float4*)(feat + (size_t)((unsigned)p.y >> 10) * 16 + c0);
                    float we = __int_as_float(p.x);
                    acc.x = fmaf(we, v.x, acc.x); acc.y = fmaf(we, v.y, acc.y);
                    acc.z = fmaf(we, v.z, acc.z); acc.w = fmaf(we, v.w, acc.w);
                }
            }
        }
        float rs = rsqrtf(fmaxf((float)cnt, 1.0f));
        float a[10];
        a[0] = __shfl(acc.x, 0, 4); a[1] = __shfl(acc.y, 0, 4);
        a[2] = __shfl(acc.z, 0, 4); a[3] = __shfl(acc.w, 0, 4);
        a[4] = __shfl(acc.x, 1, 4); a[5] = __shfl(acc.y, 1, 4);
        a[6] = __shfl(acc.z, 1, 4); a[7] = __shfl(acc.w, 1, 4);
        a[8] = __shfl(acc.x, 2, 4); a[9] = __shfl(acc.y, 2, 4);
#pragma unroll
        for (int j = 0; j < 10; j++) a[j] *= rs;
        float hh[10], z[10];
#pragma unroll
        for (int k = 0; k < 10; k++) {
            float t = sb2[k];
#pragma unroll
            for (int j = 0; j < 10; j++) t = fmaf(a[j], sW2[j * 10 + k], t);
            hh[k] = fmaxf(t, 0.0f);
        }
#pragma unroll
        for (int k = 0; k < 10; k++) {
            float t = sbo1[k];
#pragma unroll
            for (int j = 0; j < 10; j++) t = fmaf(hh[j], sWo1[j * 10 + k], t);
            z[k] = fmaxf(t, 0.0f);
        }
        float t3 = sbo3v;
#pragma unroll
        for (int k = 0; k < 10; k++) {
            float t = sbo2[k];
#pragma unroll
            for (int j = 0; j < 10; j++) t = fmaf(z[j], sWo2[j * 10 + k], t);
            t = fmaxf(t, 0.0f);
            t3 = fmaf(t, sWo3[k], t3);
        }
        if (lane == 0) accd += (double)t3;
    }
    red[tid] = accd;
    __syncthreads();
    for (int off = 256; off > 0; off >>= 1) {
        if (tid < off) red[tid] += red[tid + off];
        __syncthreads();
    }
    if (tid == 0) partials[blockIdx.x] = red[0];
}

__global__ __launch_bounds__(256) void k_out(const double* __restrict__ partials, int np,
                                             float* __restrict__ out) {
    __shared__ double red[256];
    double a = 0.0;
    for (int i = threadIdx.x; i < np; i += blockDim.x) a += partials[i];
    red[threadIdx.x] = a;
    __syncthreads();
    for (int off = 128; off > 0; off >>= 1) {
        if (threadIdx.x < off) red[threadIdx.x] += red[threadIdx.x + off];
        __syncthreads();
    }
    if (threadIdx.x == 0) out[0] = (float)(red[0] / (double)NVAR);
}

// ============================================================================
// Launch
// ============================================================================

extern "C" void kernel_launch(void* const* d_in, const int* in_sizes, int n_in,
                              void* d_out, int out_size, void* d_ws, size_t ws_size,
                              hipStream_t stream) {
    const float* var_c  = (const float*)d_in[0];
    const float* var_x  = (const float*)d_in[1];
    const int*   e_src  = (const int*)d_in[3];
    const int*   e_dst  = (const int*)d_in[4];
    const float* e_w    = (const float*)d_in[5];
    const float* Wv     = (const float*)d_in[6];
    const float* bv     = (const float*)d_in[7];
    const float* W2     = (const float*)d_in[12];
    const float* b2     = (const float*)d_in[13];
    const float* Wo1    = (const float*)d_in[14];
    const float* bo1    = (const float*)d_in[15];
    const float* Wo2    = (const float*)d_in[16];
    const float* bo2    = (const float*)d_in[17];
    const float* Wo3    = (const float*)d_in[18];
    const float* bo3    = (const float*)d_in[19];
    float* out = (float*)d_out;
    const int ne = in_sizes[3];
    (void)n_in; (void)out_size; (void)ws_size;

    const int B = 256;
    const int nblkA = (ne + EPB - 1) / EPB;       // 977
    const int scanN = 1024 * nblkA;
    const int NBs   = (scanN + 1023) / 1024;
    const int BKV   = (NVAR + 1023) >> 10;        // 977 (shift 10)
    const int BKC   = (NCON + 511) >> 9;          // 977 (shift 9)
    const int ne4   = ne / 4;

    char* ws = (char*)d_ws;
    size_t off = 0;
    auto walloc = [&](size_t bytes) {
        void* p = ws + off;
        off = (off + bytes + 255) & ~(size_t)255;
        return p;
    };

    int2*     bucketedV = (int2*)walloc((size_t)ne * 8);           // 64 MB
    int2*     bucketedC = (int2*)walloc((size_t)ne * 8);           // 64 MB
    float*    Xs64      = (float*)walloc((size_t)NVAR * 16 * 4);   // 64 MB
    float*    hs64      = (float*)walloc((size_t)NCON * 16 * 4);   // 32 MB
    unsigned* scannedV  = (unsigned*)walloc((size_t)scanN * 4);    //  4 MB
    unsigned* scannedC  = (unsigned*)walloc((size_t)scanN * 4);    //  4 MB
    unsigned* bhV       = (unsigned*)walloc((size_t)scanN * 4);    //  4 MB
    unsigned* bhC       = (unsigned*)walloc((size_t)scanN * 4);    //  4 MB
    unsigned* bsumV     = (unsigned*)walloc(4096);
    unsigned* bscanV    = (unsigned*)walloc(4096);
    unsigned* bsumC     = (unsigned*)walloc(4096);
    unsigned* bscanC    = (unsigned*)walloc(4096);
    unsigned* bdummy    = (unsigned*)walloc(256);
    // overlays: bhV dead after scanV -> deg_var; bhC dead after scanC -> partials
    unsigned* deg_var   = bhV;
    double*   partials  = (double*)bhC;           // BKV*2 doubles << 4 MB

    // 1. fused dual histogram
    kA_hist2<<<nblkA, B, 0, stream>>>((const int4*)e_src, (const int4*)e_dst,
                                      bhV, bhC, ne4, nblkA);

    // 2. scans -> global segment bases
    k_scan_blocks<<<NBs, B, 0, stream>>>(bhV, scannedV, bsumV, scanN);
    k_scan_blocks<<<1,   B, 0, stream>>>(bsumV, bscanV, bdummy, NBs);
    k_scan_add   <<<NBs, B, 0, stream>>>(scannedV, bscanV, scanN);
    k_scan_blocks<<<NBs, B, 0, stream>>>(bhC, scannedC, bsumC, scanN);
    k_scan_blocks<<<1,   B, 0, stream>>>(bsumC, bscanC, bdummy, NBs);
    k_scan_add   <<<NBs, B, 0, stream>>>(scannedC, bscanC, scanN);

    // 3. V-direction bucketing (key=src var, val=dst con)
    kA_scat<<<nblkA, B, 0, stream>>>(e_src, e_dst, e_w, scannedV, bucketedV, ne, 10, nblkA);

    // 4. deg_var (overlays bhV, dead after scanV)
    kB_degV<<<BKV, B, 0, stream>>>(bucketedV, scannedV, deg_var, NVAR, nblkA);

    // 5. var embedding (prescaled, 64 B rows)
    k_xvar_p<<<(NVAR + B - 1) / B, B, 0, stream>>>(var_c, var_x, deg_var, Wv, bv, Xs64, NVAR);

    // 6. C-direction bucketing (key=dst con, val=src var)
    kA_scat<<<nblkA, B, 0, stream>>>(e_dst, e_src, e_w, scannedC, bucketedC, ne, 9, nblkA);

    // 7. conv1 fused (half-buckets): sort-stage in LDS + register-accumulate gather
    kF_con<<<BKC * 2, 512, 0, stream>>>(bucketedC, scannedC, Xs64, W2, b2, hs64, nblkA);

    // 8. conv2 fused (half-buckets): sort-stage + gather + MLP + partial mean
    kF_fin<<<BKV * 2, 512, 0, stream>>>(bucketedV, scannedV, hs64, W2, b2,
                                        Wo1, bo1, Wo2, bo2, Wo3, bo3, partials, nblkA);

    // 9. final mean
    k_out<<<1, B, 0, stream>>>(partials, BKV * 2, out);
}